// Round 10
// baseline (8119.950 us; speedup 1.0000x reference)
//
#include <hip/hip_runtime.h>

// Problem constants
#define B_   32
#define T_   256
#define N_   128
#define DIN_ 16
#define U_   64

// LDS (ushort): diffb [128 nodes][PD] node-major; difT [128 ch][PT] ch-major
// PD/PT chosen so row stride mod 32 banks = 6 (was 4 -> 8-way conflicts on
// every ds_read_b128) while keeping stride mod 8 B == 0 for ull/us4 alignment.
#define PD 460
#define PT 140
#define LDS_BYTES ((N_*PD + N_*PT)*2)   // 153600 B

// Workspace (ushort elems)
#define WT0G_OFF 0
#define WT0C_OFF (128*256)
#define WT1G_OFF (WT0C_OFF + 64*256)
#define WT1C_OFF (WT1G_OFF + 128*384)
#define WT_TOTAL (WT1C_OFF + 64*384)
#define S2_OFF   WT_TOTAL                 // bf16 S2[128][128]
#define FIFO_OFF (S2_OFF + 128*128)       // h0' stream: [b][t%8] x 8192 ush (16KB)
#define FIFO_SLOT(bb,tt) (FIFO_OFF + ((bb)*8 + ((tt)&7))*8192)
// flags: 2048 ints (8KB). prod[b] at flg[b*32] (one 128B line per batch);
// cons[b] at flg[1024 + b*32].
#define FLG_BYTE ((FIFO_OFF + 32*8*8192)*2)
#define FLG_USH  4096
// dm12 stream: [b][t%4] x 16384 ush (32KB) — byte image of diffb cols 64-191 per node
#define FIFO2_OFF (FIFO_OFF + 32*8*8192 + FLG_USH)
#define FIFO2_SLOT(bb,tt) (FIFO2_OFF + ((bb)*4 + ((tt)&3))*16384)

typedef __attribute__((ext_vector_type(8))) short bfrag;
typedef __attribute__((ext_vector_type(4))) float ffrag;
typedef __attribute__((ext_vector_type(4))) unsigned short us4;
typedef __attribute__((ext_vector_type(2))) unsigned short us2;
typedef unsigned long long ull;

// LDS-only barrier (no vmcnt drain)
#define SYNC() asm volatile("s_waitcnt lgkmcnt(0)\n\ts_barrier" ::: "memory")
#define MFMA16(a,b,c) __builtin_amdgcn_mfma_f32_16x16x32_bf16(a,b,c,0,0,0)

__device__ __forceinline__ unsigned short f2b(float x) {
  union { float f; unsigned u; } v; v.f = x;
  return (unsigned short)((v.u + 0x7fffu + ((v.u >> 16) & 1u)) >> 16);
}
__device__ __forceinline__ float sigm(float x) {
  float e = __expf(-x);
  return __builtin_amdgcn_rcpf(1.f + e);
}
__device__ __forceinline__ float tanh_(float x) {
  float e = __expf(2.f * x);
  return 1.f - 2.f * __builtin_amdgcn_rcpf(1.f + e);
}

// L0 gate k-map (K=256): [x dm0 16 | x dm12 32 | zero 16 | h dm0 64 | h dm12 128]
__device__ __forceinline__ float wval0(const float* w, int ncol, int co, int k) {
  if (k < 16)  return w[(k*3+0)*ncol+co] - w[(k*3+2)*ncol+co];
  if (k < 48)  { int j=k-16, c=j>>1;
                 return (j&1) ? 2.f*w[(c*3+2)*ncol+co] : w[(c*3+1)*ncol+co]; }
  if (k < 64)  return 0.f;
  if (k < 128) { int c=16+(k-64); return w[(c*3+0)*ncol+co] - w[(c*3+2)*ncol+co]; }
  { int j=k-128, c=16+(j>>1);
    return (j&1) ? 2.f*w[(c*3+2)*ncol+co] : w[(c*3+1)*ncol+co]; }
}
// L1 gate k-map (K=384): [h0' dm0 64 | h0' dm12 128 | h1 dm0 64 | h1 dm12 128]
__device__ __forceinline__ float wval1(const float* w, int ncol, int co, int k) {
  if (k < 64)  return w[(k*3+0)*ncol+co] - w[(k*3+2)*ncol+co];
  if (k < 192) { int j=k-64, c=j>>1;
                 return (j&1) ? 2.f*w[(c*3+2)*ncol+co] : w[(c*3+1)*ncol+co]; }
  if (k < 256) { int c=64+(k-192); return w[(c*3+0)*ncol+co] - w[(c*3+2)*ncol+co]; }
  { int j=k-256, c=64+(j>>1);
    return (j&1) ? 2.f*w[(c*3+2)*ncol+co] : w[(c*3+1)*ncol+co]; }
}
// cand k-orders (rh double-buffered):
// L0 cand cols: [x/zero 0-63 | rh dm12 @128-255 | rh dm0 @256-319]
__device__ __forceinline__ float wval0c(const float* w, int ncol, int co, int k) {
  if (k < 64)  return wval0(w, ncol, co, k);
  if (k < 192) return wval0(w, ncol, co, k + 64);
  return wval0(w, ncol, co, k - 128);
}
// L1 cand cols: [h0' 0-191 | rh dm12 @256-383 | rh dm0 @384-447]
__device__ __forceinline__ float wval1c(const float* w, int ncol, int co, int k) {
  if (k < 192) return wval1(w, ncol, co, k);
  if (k < 320) return wval1(w, ncol, co, k + 64);
  return wval1(w, ncol, co, k - 128);
}

__global__ void setup_wt(const float* __restrict__ w0g, const float* __restrict__ w0c,
                         const float* __restrict__ w1g, const float* __restrict__ w1c,
                         unsigned short* __restrict__ wt) {
  int i = blockIdx.x * blockDim.x + threadIdx.x;
  if (i >= WT_TOTAL) return;
  float v;
  if (i < WT0C_OFF)      { int co = i >> 8, k = i & 255;                 v = wval0 (w0g, 128, co, k); }
  else if (i < WT1G_OFF) { int j = i - WT0C_OFF; v = wval0c(w0c, 64, j >> 8, j & 255); }
  else if (i < WT1C_OFF) { int j = i - WT1G_OFF; v = wval1 (w1g, 128, j / 384, j % 384); }
  else                   { int j = i - WT1C_OFF; v = wval1c(w1c, 64, j / 384, j % 384); }
  wt[i] = f2b(v);
}

__global__ void setup_s2(const float* __restrict__ sup, unsigned short* __restrict__ s2) {
  int idx = blockIdx.x * blockDim.x + threadIdx.x;
  int i = idx >> 7, j = idx & 127;
  float acc = 0.f;
#pragma unroll 4
  for (int k = 0; k < 128; ++k) acc += sup[i*128 + k] * sup[k*128 + j];
  s2[idx] = f2b(acc);
}

__global__ void zero_flags(unsigned short* __restrict__ wt) {
  int* flg = (int*)((char*)wt + FLG_BYTE);
  for (int i = threadIdx.x; i < 2048; i += blockDim.x) flg[i] = 0;
}

// Gate GEMM, REGISTER-RESIDENT weights: 4 m-tiles x {r,u}; zero vm ops in loop.
template<int KT>
__device__ __forceinline__ void gateR(ffrag (&acc)[4][2],
    const bfrag (&bwr)[KT], const bfrag (&bwu)[KT],
    const unsigned short* __restrict__ arowB, const int lq) {
#pragma unroll
  for (int ks = 0; ks < KT; ++ks) {
    bfrag a[4];
#pragma unroll
    for (int i = 0; i < 4; ++i)
      a[i] = *(const bfrag*)&arowB[16*i*PD + 32*ks + 8*lq];
#pragma unroll
    for (int i = 0; i < 4; ++i) {
      acc[i][0] = MFMA16(a[i], bwr[ks], acc[i][0]);
      acc[i][1] = MFMA16(a[i], bwu[ks], acc[i][1]);
    }
  }
}
// Cand GEMM: 4 m-tiles x 1 co; A-cols via ks-offset list; 4-deep streamed ring.
template<int KT>
__device__ __forceinline__ void candR(ffrag (&acc)[4], bfrag (&bw)[4],
    const unsigned short* __restrict__ arowB, const int (&kofs)[KT],
    const unsigned short* __restrict__ bpc, const int lq) {
#pragma unroll
  for (int ks = 0; ks < KT; ++ks) {
    const int k = ks & 3;
    bfrag a[4];
#pragma unroll
    for (int i = 0; i < 4; ++i)
      a[i] = *(const bfrag*)&arowB[16*i*PD + kofs[ks] + 8*lq];
    bfrag bc = bw[k];
    if (ks + 4 < KT) bw[k] = *(const bfrag*)&bpc[32*(ks+4) + 8*lq];
#pragma unroll
    for (int i = 0; i < 4; ++i) acc[i] = MFMA16(a[i], bc, acc[i]);
  }
}

__global__ __launch_bounds__(512, 2) void dcgru(
    const float* __restrict__ xseq, const int* __restrict__ slen,
    const float* __restrict__ sup,
    const float* __restrict__ b0g, const float* __restrict__ b0c,
    const float* __restrict__ b1g, const float* __restrict__ b1c,
    const float* __restrict__ wfc, const float* __restrict__ bfc,
    unsigned short* __restrict__ wt, float* __restrict__ out) {
  extern __shared__ unsigned short lds[];
  unsigned short* diffb = lds;
  unsigned short* difT  = lds + N_*PD;
  // XCD-local A/B pairing (A=x, B=x+8 share XCD under round-robin dispatch)
  const int b    = (blockIdx.x & 7) | ((blockIdx.x >> 4) << 3);
  const int eta  = (blockIdx.x >> 3) & 1;
  const int tid  = threadIdx.x;
  const int w    = tid >> 6;              // wave 0..7
  const int j    = w & 3;                 // ch-tile: ch [16j, 16j+16)
  const int g    = w >> 2;                // node-half: m-tiles 4g..4g+3 (64 nodes)
  const int ln   = tid & 15;
  const int lq   = (tid >> 4) & 3;
  const int L    = slen[b];
  int* flg  = (int*)((char*)wt + FLG_BYTE);
  int* prod = flg + b*32;                 // private 128B line per batch
  int* cons = flg + 1024 + b*32;          // private 128B line per batch
  const unsigned short* __restrict__ arowB = diffb + (64*g + ln)*PD;
  const ffrag fz = {0.f, 0.f, 0.f, 0.f};

  // S / S2 A-frags for diffuse strip w (1 strip, 8 bfrags = 32 VGPR)
  bfrag Sf[4], S2f[4];
#pragma unroll
  for (int ks = 0; ks < 4; ++ks) {
    const float* pS = sup + (16*w + ln)*N_ + 32*ks + 8*lq;
    union { bfrag v; unsigned short u[8]; } tmp;
#pragma unroll
    for (int jj = 0; jj < 8; ++jj) tmp.u[jj] = f2b(pS[jj]);
    Sf[ks] = tmp.v;
    S2f[ks] = *(const bfrag*)&wt[S2_OFF + (16*w + ln)*N_ + 32*ks + 8*lq];
  }

  // diffuse ch-tile nt for strip w: dm1=S@xc, dm2=S2@xc; cols colc + 2*ln + {0,1}
  auto diffuse = [&](int nt, int colc) {
    bfrag bf[4];
#pragma unroll
    for (int ks = 0; ks < 4; ++ks)
      bf[ks] = *(const bfrag*)&difT[(16*nt + ln)*PT + 32*ks + 8*lq];
    ffrag a1 = fz, a2 = fz;
#pragma unroll
    for (int ks = 0; ks < 4; ++ks) {
      a1 = MFMA16(Sf[ks],  bf[ks], a1);
      a2 = MFMA16(S2f[ks], bf[ks], a2);
    }
    const int n0 = 16*w + 4*lq;
    const int col = colc + 2*ln;
#pragma unroll
    for (int r = 0; r < 4; ++r) {
      us2 pq = {f2b(a1[r]), f2b(a2[r])};
      *(us2*)&diffb[(n0 + r)*PD + col] = pq;
    }
  };
  // dump wave's 4m x 1ch C-frags into both layouts
  auto dumpCell = [&](ffrag (&v)[4], int colBase, int rowBase) {
    const int chh = 16*j + ln;
#pragma unroll
    for (int i = 0; i < 4; ++i) {
      const int n0 = 64*g + 16*i + 4*lq;
      unsigned short sv[4];
#pragma unroll
      for (int r = 0; r < 4; ++r) sv[r] = f2b(v[i][r]);
#pragma unroll
      for (int r = 0; r < 4; ++r) diffb[(n0 + r)*PD + colBase + chh] = sv[r];
      us4 q = {sv[0], sv[1], sv[2], sv[3]};
      *(us4*)&difT[(rowBase + chh)*PT + n0] = q;
    }
  };
  auto prebC = [&](bfrag (&bw)[4], const unsigned short* bpc) {
#pragma unroll
    for (int k = 0; k < 4; ++k) bw[k] = *(const bfrag*)&bpc[32*k + 8*lq];
  };
  auto waitge = [&](int* p, int seq) {
    if ((tid & 63) == 0) {
      int it = 0;
      while (__hip_atomic_load(p, __ATOMIC_RELAXED, __HIP_MEMORY_SCOPE_AGENT) < seq) {
        __builtin_amdgcn_s_sleep(1);
        if (++it > (1 << 24)) break;            // failsafe: never hard-hang
      }
    }
  };

  bfrag bw4[4];

  if (eta == 0) {
    // ===== Block A: L0. cols [x 0-15|x dm12 16-47|z 48-63|h dm0 64-127|h dm12 128-255|rh dm0 256-319]
    // h0' dm12 (cols 128-255) is computed at END of each step (after cand) and
    // shipped to B via FIFO2 — B does not re-diffuse h0'.
    bfrag bwr[8], bwu[8];
    {
      const unsigned short* bpr = wt + WT0G_OFF + (16*j      + ln)*256;
      const unsigned short* bpu = wt + WT0G_OFF + (16*(4+j)  + ln)*256;
#pragma unroll
      for (int ks = 0; ks < 8; ++ks) {
        bwr[ks] = *(const bfrag*)&bpr[32*ks + 8*lq];
        bwu[ks] = *(const bfrag*)&bpu[32*ks + 8*lq];
      }
    }
    const unsigned short* bpc = wt + WT0C_OFF + (16*j + ln)*256;
    const float bgr = b0g[16*j + ln], bgu = b0g[64 + 16*j + ln];
    const float bcv = b0c[16*j + ln];
    const int kofs0[8] = {0, 32, 128, 160, 192, 224, 256, 288};
    ffrag h0m[4] = {fz, fz, fz, fz};

    // zero cols [48,256): zero-pad block + h dm0 + h dm12 for t=0 (h0 = 0)
    for (int i = tid; i < N_*208; i += 512) {
      int row = i / 208, c = i - row*208;
      diffb[row*PD + 48 + c] = 0;
    }
    float4 xv = *(const float4*)&xseq[(size_t)(b*T_)*N_*DIN_ + 4*tid];

#pragma clang loop unroll(disable)
    for (int t = 0; t < L; ++t) {
      { // P1: stage x (cols 0-15 / difT rows 0-15). h-dumps moved to step end.
        const int node = tid >> 2, c = 4*(tid & 3);
        unsigned short s0 = f2b(xv.x), s1 = f2b(xv.y), s2 = f2b(xv.z), s3 = f2b(xv.w);
        us4 q = {s0, s1, s2, s3};
        *(us4*)&diffb[node*PD + c] = q;
        difT[(c+0)*PT + node] = s0; difT[(c+1)*PT + node] = s1;
        difT[(c+2)*PT + node] = s2; difT[(c+3)*PT + node] = s3;
        int tn = t + 1 < L ? t + 1 : L - 1;
        xv = *(const float4*)&xseq[(size_t)(b*T_ + tn)*N_*DIN_ + 4*tid];
      }
      SYNC();                                            // BAR1
      diffuse(0, 16);                                    // x dm12 only
      SYNC();                                            // BAR2
      ffrag u0s[4], rh[4];
      {
        ffrag ga[4][2] = {{fz, fz}, {fz, fz}, {fz, fz}, {fz, fz}};
        gateR<8>(ga, bwr, bwu, arowB, lq);
#pragma unroll
      for (int i = 0; i < 4; ++i)
#pragma unroll
          for (int r = 0; r < 4; ++r) {
            float rr = sigm(ga[i][0][r] + bgr);
            rh[i][r]  = rr * h0m[i][r];
            u0s[i][r] = sigm(ga[i][1][r] + bgu);
          }
      }
      dumpCell(rh, 256, 16);                 // rh dm0 -> fresh cols (no gate WAR)
      prebC(bw4, bpc);
      SYNC();                                            // BAR3
      diffuse(1, 128); diffuse(2, 160); diffuse(3, 192); diffuse(4, 224);  // rh dm12
      SYNC();                                            // BAR4
      {
        ffrag ca[4] = {fz, fz, fz, fz};
        candR<8>(ca, bw4, arowB, kofs0, bpc, lq);
#pragma unroll
        for (int i = 0; i < 4; ++i)
#pragma unroll
          for (int r = 0; r < 4; ++r) {
            float cc = tanh_(ca[i][r] + bcv);
            float uu = u0s[i][r];
            h0m[i][r] = uu*h0m[i][r] + (1.f - uu)*cc;
          }
      }
      // h0'(t) ready. Dump both layouts (cols 64-127 disjoint from cand reads).
      dumpCell(h0m, 64, 16);
      if (t >= 4) waitge(cons, t - 3);                   // FIFO2 depth-4 backpressure
      { // send h0' ch-major [64 ch][128 nodes] (register source)
        unsigned short* slot = wt + FIFO_SLOT(b, t);
        const int chh = 16*j + ln;
#pragma unroll
        for (int i = 0; i < 4; ++i) {
          const int n0 = 64*g + 16*i + 4*lq;
          us4 q = {f2b(h0m[i][0]), f2b(h0m[i][1]), f2b(h0m[i][2]), f2b(h0m[i][3])};
          *(us4*)&slot[chh*128 + n0] = q;
        }
      }
      SYNC();                                            // BAR5: h0' difT dump visible
      // h0' dm12 -> cols 128-255 (reused by next-step gate AND sent to B)
      diffuse(1, 128); diffuse(2, 160); diffuse(3, 192); diffuse(4, 224);
      SYNC();                                            // BAR6: dm12 image complete
      { // ship byte image of cols [128,256) -> FIFO2 (B maps to its cols [64,192))
        unsigned short* slot2 = wt + FIFO2_SLOT(b, t);
#pragma unroll
        for (int rep = 0; rep < 8; ++rep) {
          const int i = tid + 512*rep;
          const int node = i >> 5, off = (i & 31)*4;
          ull v = *(const ull*)&diffb[node*PD + 128 + off];
          *(ull*)&slot2[node*128 + off] = v;
        }
      }
      asm volatile("s_waitcnt vmcnt(0)" ::: "memory");    // drain both payloads
      if ((tid & 63) == 0)
        __hip_atomic_fetch_add(prod, 1, __ATOMIC_RELEASE, __HIP_MEMORY_SCOPE_AGENT);
    }
    return;
  }

  // ===== Block B: L1. cols [h0' dm0 0-63|h0' dm12 64-191|h1 dm0 192-255|h1/rh dm12 256-383|rh dm0 384-447]
  {
    // Resident gate weights: r_j, u_j, K=384 (24 bfrags = 96 VGPR)
    bfrag bwr[12], bwu[12];
    {
      const unsigned short* bpr = wt + WT1G_OFF + (16*j     + ln)*384;
      const unsigned short* bpu = wt + WT1G_OFF + (16*(4+j) + ln)*384;
#pragma unroll
      for (int ks = 0; ks < 12; ++ks) {
        bwr[ks] = *(const bfrag*)&bpr[32*ks + 8*lq];
        bwu[ks] = *(const bfrag*)&bpu[32*ks + 8*lq];
      }
    }
    const unsigned short* bpc = wt + WT1C_OFF + (16*j + ln)*384;
    const float bgr = b1g[16*j + ln], bgu = b1g[64 + 16*j + ln];
    const float bcv = b1c[16*j + ln];
    const int kofs1[12] = {0, 32, 64, 96, 128, 160, 256, 288, 320, 352, 384, 416};
    ffrag h1m[4] = {fz, fz, fz, fz};

#pragma clang loop unroll(disable)
    for (int t = 0; t < L; ++t) {
      waitge(prod, 8*(t + 1));               // all 8 A-waves published step t
      { // P1: recv h0'(t) -> diffb cols 0-63 + difT rows 0-63; dm12 image -> cols 64-191;
        // dump h1 (cols 192-255 / difT rows 64-127)
        const unsigned short* slot = wt + FIFO_SLOT(b, t);
#pragma unroll
        for (int rep = 0; rep < 4; ++rep) {
          const int idx = tid + 512*rep;
          const int ch = idx >> 5, n0 = (idx & 31)*4;
          ull v = __hip_atomic_load((const ull*)&slot[ch*128 + n0],
                                    __ATOMIC_RELAXED, __HIP_MEMORY_SCOPE_AGENT);
          *(ull*)&difT[ch*PT + n0] = v;
          union { ull u; unsigned short s[4]; } cv; cv.u = v;
#pragma unroll
          for (int jj = 0; jj < 4; ++jj) diffb[(n0 + jj)*PD + ch] = cv.s[jj];
        }
        const unsigned short* slot2 = wt + FIFO2_SLOT(b, t);
#pragma unroll
        for (int rep = 0; rep < 8; ++rep) {
          const int i = tid + 512*rep;
          const int node = i >> 5, off = (i & 31)*4;
          ull v = __hip_atomic_load((const ull*)&slot2[node*128 + off],
                                    __ATOMIC_RELAXED, __HIP_MEMORY_SCOPE_AGENT);
          *(ull*)&diffb[node*PD + 64 + off] = v;
        }
        dumpCell(h1m, 192, 64);
      }
      SYNC();                                            // BAR1
      if (tid == 0)
        __hip_atomic_fetch_add(cons, 1, __ATOMIC_RELEASE, __HIP_MEMORY_SCOPE_AGENT);
      diffuse(4, 256); diffuse(5, 288); diffuse(6, 320); diffuse(7, 352);  // h1 dm12 only
      SYNC();                                            // BAR2
      ffrag u1s[4], rh[4];
      {
        ffrag ga[4][2] = {{fz, fz}, {fz, fz}, {fz, fz}, {fz, fz}};
        gateR<12>(ga, bwr, bwu, arowB, lq);
#pragma unroll
        for (int i = 0; i < 4; ++i)
#pragma unroll
          for (int r = 0; r < 4; ++r) {
            float rr = sigm(ga[i][0][r] + bgr);
            rh[i][r]  = rr * h1m[i][r];
            u1s[i][r] = sigm(ga[i][1][r] + bgu);
          }
      }
      dumpCell(rh, 384, 64);                 // rh dm0 -> fresh cols
      prebC(bw4, bpc);
      SYNC();                                            // BAR3
      diffuse(4, 256); diffuse(5, 288); diffuse(6, 320); diffuse(7, 352);  // rh dm12
      SYNC();                                            // BAR4
      {
        ffrag ca[4] = {fz, fz, fz, fz};
        candR<12>(ca, bw4, arowB, kofs1, bpc, lq);
#pragma unroll
        for (int i = 0; i < 4; ++i)
#pragma unroll
          for (int r = 0; r < 4; ++r) {
            float cc = tanh_(ca[i][r] + bcv);
            float uu = u1s[i][r];
            h1m[i][r] = uu*h1m[i][r] + (1.f - uu)*cc;
          }
      }
      SYNC();                                            // BAR5 (cand reads done)
    }

    // Head: relu(h1) @ W_fc + b_fc, max over nodes
    {
      float* hb = (float*)lds;                  // [128][64]
#pragma unroll
      for (int i = 0; i < 4; ++i)
#pragma unroll
        for (int r = 0; r < 4; ++r) {
          float v = h1m[i][r];
          hb[(64*g + 16*i + 4*lq + r)*U_ + 16*j + ln] = v > 0.f ? v : 0.f;
        }
    }
    __syncthreads();
    float* hb = (float*)lds;
    float* lb = hb + N_*U_;
    if (tid < N_) {
      float lg[4];
#pragma unroll
      for (int jj = 0; jj < 4; ++jj) lg[jj] = bfc[jj];
      for (int ch = 0; ch < U_; ++ch) {
        float v = hb[tid*U_ + ch];
#pragma unroll
        for (int jj = 0; jj < 4; ++jj) lg[jj] += v * wfc[ch*4 + jj];
      }
#pragma unroll
      for (int jj = 0; jj < 4; ++jj) lb[tid*4 + jj] = lg[jj];
    }
    __syncthreads();
    if (tid < 4) {
      float m = lb[tid];
      for (int n = 1; n < N_; ++n) m = fmaxf(m, lb[n*4 + tid]);
      out[b*4 + tid] = m;
    }
  }
}

extern "C" void kernel_launch(void* const* d_in, const int* in_sizes, int n_in,
                              void* d_out, int out_size, void* d_ws, size_t ws_size,
                              hipStream_t stream) {
  const float* xseq = (const float*)d_in[0];
  const int*   slen = (const int*)  d_in[1];
  const float* sup  = (const float*)d_in[2];
  const float* w0g  = (const float*)d_in[3];
  const float* b0g  = (const float*)d_in[4];
  const float* w0c  = (const float*)d_in[5];
  const float* b0c  = (const float*)d_in[6];
  const float* w1g  = (const float*)d_in[7];
  const float* b1g  = (const float*)d_in[8];
  const float* w1c  = (const float*)d_in[9];
  const float* b1c  = (const float*)d_in[10];
  const float* wfc  = (const float*)d_in[11];
  const float* bfc  = (const float*)d_in[12];
  float* out = (float*)d_out;
  unsigned short* wt = (unsigned short*)d_ws;

  (void)hipFuncSetAttribute((const void*)dcgru,
                            hipFuncAttributeMaxDynamicSharedMemorySize, LDS_BYTES);
  zero_flags<<<dim3(1), dim3(512), 0, stream>>>(wt);
  setup_wt<<<dim3((WT_TOTAL + 255)/256), dim3(256), 0, stream>>>(w0g, w0c, w1g, w1c, wt);
  setup_s2<<<dim3(64), dim3(256), 0, stream>>>(sup, wt + S2_OFF);
  dcgru<<<dim3(64), dim3(512), LDS_BYTES, stream>>>(
      xseq, slen, sup, b0g, b0c, b1g, b1c, wfc, bfc, wt, out);
}

// Round 11
// 4492.016 us; speedup vs baseline: 1.8076x; 1.8076x over previous
//
#include <hip/hip_runtime.h>

// Problem constants
#define B_   32
#define T_   256
#define N_   128
#define DIN_ 16
#define U_   64

// LDS (ushort): diffb [128 nodes][PD] node-major; difT [80 ch-rows][PT] ch-major
// Merged-layer column map (both layers in one block, sequential per step):
// [x 0-15 | x dm12 16-47 | zero 48-63 | h0 dm0 64-127 | h0/rh0 dm12 128-255 |
//  rh0/rh1 dm0 256-319 | h1 dm0 320-383 | h1/rh1 dm12 384-511]
// PD=520: row stride 1040B = 65*16 (b128-aligned), 260 dw = 4 mod 32 banks.
#define PD 520
#define PT 136
#define DT_ROWS 80
#define LDS_BYTES ((N_*PD + DT_ROWS*PT)*2)   // 154880 B

// Workspace (ushort elems): weights + S2 only — no FIFO, no flags.
#define WT0G_OFF 0
#define WT0C_OFF (128*256)
#define WT1G_OFF (WT0C_OFF + 64*256)
#define WT1C_OFF (WT1G_OFF + 128*384)
#define WT_TOTAL (WT1C_OFF + 64*384)
#define S2_OFF   WT_TOTAL                 // bf16 S2[128][128]

typedef __attribute__((ext_vector_type(8))) short bfrag;
typedef __attribute__((ext_vector_type(4))) float ffrag;
typedef __attribute__((ext_vector_type(4))) unsigned short us4;
typedef __attribute__((ext_vector_type(2))) unsigned short us2;
typedef unsigned long long ull;

// LDS-only barrier (no vmcnt drain)
#define SYNC() asm volatile("s_waitcnt lgkmcnt(0)\n\ts_barrier" ::: "memory")
#define MFMA16(a,b,c) __builtin_amdgcn_mfma_f32_16x16x32_bf16(a,b,c,0,0,0)

__device__ __forceinline__ unsigned short f2b(float x) {
  union { float f; unsigned u; } v; v.f = x;
  return (unsigned short)((v.u + 0x7fffu + ((v.u >> 16) & 1u)) >> 16);
}
__device__ __forceinline__ float sigm(float x) {
  float e = __expf(-x);
  return __builtin_amdgcn_rcpf(1.f + e);
}
__device__ __forceinline__ float tanh_(float x) {
  float e = __expf(2.f * x);
  return 1.f - 2.f * __builtin_amdgcn_rcpf(1.f + e);
}

// L0 gate k-map (K=256): [x dm0 16 | x dm12 32 | zero 16 | h dm0 64 | h dm12 128]
__device__ __forceinline__ float wval0(const float* w, int ncol, int co, int k) {
  if (k < 16)  return w[(k*3+0)*ncol+co] - w[(k*3+2)*ncol+co];
  if (k < 48)  { int j=k-16, c=j>>1;
                 return (j&1) ? 2.f*w[(c*3+2)*ncol+co] : w[(c*3+1)*ncol+co]; }
  if (k < 64)  return 0.f;
  if (k < 128) { int c=16+(k-64); return w[(c*3+0)*ncol+co] - w[(c*3+2)*ncol+co]; }
  { int j=k-128, c=16+(j>>1);
    return (j&1) ? 2.f*w[(c*3+2)*ncol+co] : w[(c*3+1)*ncol+co]; }
}
// L1 gate k-map (K=384): [h0' dm0 64 | h0' dm12 128 | h1 dm0 64 | h1 dm12 128]
__device__ __forceinline__ float wval1(const float* w, int ncol, int co, int k) {
  if (k < 64)  return w[(k*3+0)*ncol+co] - w[(k*3+2)*ncol+co];
  if (k < 192) { int j=k-64, c=j>>1;
                 return (j&1) ? 2.f*w[(c*3+2)*ncol+co] : w[(c*3+1)*ncol+co]; }
  if (k < 256) { int c=64+(k-192); return w[(c*3+0)*ncol+co] - w[(c*3+2)*ncol+co]; }
  { int j=k-256, c=64+(j>>1);
    return (j&1) ? 2.f*w[(c*3+2)*ncol+co] : w[(c*3+1)*ncol+co]; }
}
// cand k-orders:
// L0 cand cols: [x/zero 0-63 | rh dm12 @128-255 | rh dm0 @256-319]
__device__ __forceinline__ float wval0c(const float* w, int ncol, int co, int k) {
  if (k < 64)  return wval0(w, ncol, co, k);
  if (k < 192) return wval0(w, ncol, co, k + 64);
  return wval0(w, ncol, co, k - 128);
}
// L1 cand: [h0' 0-191 | rh dm12 | rh dm0]
__device__ __forceinline__ float wval1c(const float* w, int ncol, int co, int k) {
  if (k < 192) return wval1(w, ncol, co, k);
  if (k < 320) return wval1(w, ncol, co, k + 64);
  return wval1(w, ncol, co, k - 128);
}

__global__ void setup_wt(const float* __restrict__ w0g, const float* __restrict__ w0c,
                         const float* __restrict__ w1g, const float* __restrict__ w1c,
                         unsigned short* __restrict__ wt) {
  int i = blockIdx.x * blockDim.x + threadIdx.x;
  if (i >= WT_TOTAL) return;
  float v;
  if (i < WT0C_OFF)      { int co = i >> 8, k = i & 255;                 v = wval0 (w0g, 128, co, k); }
  else if (i < WT1G_OFF) { int j = i - WT0C_OFF; v = wval0c(w0c, 64, j >> 8, j & 255); }
  else if (i < WT1C_OFF) { int j = i - WT1G_OFF; v = wval1 (w1g, 128, j / 384, j % 384); }
  else                   { int j = i - WT1C_OFF; v = wval1c(w1c, 64, j / 384, j % 384); }
  wt[i] = f2b(v);
}

__global__ void setup_s2(const float* __restrict__ sup, unsigned short* __restrict__ s2) {
  int idx = blockIdx.x * blockDim.x + threadIdx.x;
  int i = idx >> 7, j = idx & 127;
  float acc = 0.f;
#pragma unroll 4
  for (int k = 0; k < 128; ++k) acc += sup[i*128 + k] * sup[k*128 + j];
  s2[idx] = f2b(acc);
}

// Gate GEMM, STREAMED weights (4-deep ring, r+u), offset-list A-cols; 4 m-tiles.
template<int KT>
__device__ __forceinline__ void gateO(ffrag (&acc)[4][2],
    bfrag (&br)[4], bfrag (&bu)[4],
    const unsigned short* __restrict__ bpr, const unsigned short* __restrict__ bpu,
    const unsigned short* __restrict__ arowB, const int (&kofs)[KT], const int lq) {
#pragma unroll
  for (int ks = 0; ks < KT; ++ks) {
    const int k = ks & 3;
    bfrag a[4];
#pragma unroll
    for (int i = 0; i < 4; ++i)
      a[i] = *(const bfrag*)&arowB[16*i*PD + kofs[ks] + 8*lq];
    bfrag rc = br[k], uc = bu[k];
    if (ks + 4 < KT) {
      br[k] = *(const bfrag*)&bpr[32*(ks+4) + 8*lq];
      bu[k] = *(const bfrag*)&bpu[32*(ks+4) + 8*lq];
    }
#pragma unroll
    for (int i = 0; i < 4; ++i) {
      acc[i][0] = MFMA16(a[i], rc, acc[i][0]);
      acc[i][1] = MFMA16(a[i], uc, acc[i][1]);
    }
  }
}
// Cand GEMM: 4 m-tiles x 1 co; A-cols via ks-offset list; 4-deep streamed ring.
template<int KT>
__device__ __forceinline__ void candR(ffrag (&acc)[4], bfrag (&bw)[4],
    const unsigned short* __restrict__ arowB, const int (&kofs)[KT],
    const unsigned short* __restrict__ bpc, const int lq) {
#pragma unroll
  for (int ks = 0; ks < KT; ++ks) {
    const int k = ks & 3;
    bfrag a[4];
#pragma unroll
    for (int i = 0; i < 4; ++i)
      a[i] = *(const bfrag*)&arowB[16*i*PD + kofs[ks] + 8*lq];
    bfrag bc = bw[k];
    if (ks + 4 < KT) bw[k] = *(const bfrag*)&bpc[32*(ks+4) + 8*lq];
#pragma unroll
    for (int i = 0; i < 4; ++i) acc[i] = MFMA16(a[i], bc, acc[i]);
  }
}

__global__ __launch_bounds__(512, 2) void dcgru(
    const float* __restrict__ xseq, const int* __restrict__ slen,
    const float* __restrict__ sup,
    const float* __restrict__ b0g, const float* __restrict__ b0c,
    const float* __restrict__ b1g, const float* __restrict__ b1c,
    const float* __restrict__ wfc, const float* __restrict__ bfc,
    unsigned short* __restrict__ wt, float* __restrict__ out) {
  extern __shared__ unsigned short lds[];
  unsigned short* diffb = lds;
  unsigned short* difT  = lds + N_*PD;
  const int b    = blockIdx.x;            // one block per batch; no pairing
  const int tid  = threadIdx.x;
  const int w    = tid >> 6;              // wave 0..7
  const int j    = w & 3;                 // ch-tile: ch [16j, 16j+16)
  const int g    = w >> 2;                // node-half: m-tiles 4g..4g+3 (64 nodes)
  const int ln   = tid & 15;
  const int lq   = (tid >> 4) & 3;
  const int L    = slen[b];
  const unsigned short* __restrict__ arowB = diffb + (64*g + ln)*PD;
  const ffrag fz = {0.f, 0.f, 0.f, 0.f};

  // S / S2 A-frags for diffuse strip w (8 bfrags = 32 VGPR)
  bfrag Sf[4], S2f[4];
#pragma unroll
  for (int ks = 0; ks < 4; ++ks) {
    const float* pS = sup + (16*w + ln)*N_ + 32*ks + 8*lq;
    union { bfrag v; unsigned short u[8]; } tmp;
#pragma unroll
    for (int jj = 0; jj < 8; ++jj) tmp.u[jj] = f2b(pS[jj]);
    Sf[ks] = tmp.v;
    S2f[ks] = *(const bfrag*)&wt[S2_OFF + (16*w + ln)*N_ + 32*ks + 8*lq];
  }

  // diffuse ch-tile nt (difT rows 16nt..16nt+15): dm1=S@xc, dm2=S2@xc
  auto diffuse = [&](int nt, int colc) {
    bfrag bf[4];
#pragma unroll
    for (int ks = 0; ks < 4; ++ks)
      bf[ks] = *(const bfrag*)&difT[(16*nt + ln)*PT + 32*ks + 8*lq];
    ffrag a1 = fz, a2 = fz;
#pragma unroll
    for (int ks = 0; ks < 4; ++ks) {
      a1 = MFMA16(Sf[ks],  bf[ks], a1);
      a2 = MFMA16(S2f[ks], bf[ks], a2);
    }
    const int n0 = 16*w + 4*lq;
    const int col = colc + 2*ln;
#pragma unroll
    for (int r = 0; r < 4; ++r) {
      us2 pq = {f2b(a1[r]), f2b(a2[r])};
      *(us2*)&diffb[(n0 + r)*PD + col] = pq;
    }
  };
  // dump wave's 4m x 1ch C-frags into both layouts (difT rows 16-79 shared)
  auto dumpCell = [&](ffrag (&v)[4], int colBase) {
    const int chh = 16*j + ln;
#pragma unroll
    for (int i = 0; i < 4; ++i) {
      const int n0 = 64*g + 16*i + 4*lq;
      unsigned short sv[4];
#pragma unroll
      for (int r = 0; r < 4; ++r) sv[r] = f2b(v[i][r]);
#pragma unroll
      for (int r = 0; r < 4; ++r) diffb[(n0 + r)*PD + colBase + chh] = sv[r];
      us4 q = {sv[0], sv[1], sv[2], sv[3]};
      *(us4*)&difT[(16 + chh)*PT + n0] = q;
    }
  };
  auto preb4 = [&](bfrag (&bw)[4], const unsigned short* bp) {
#pragma unroll
    for (int k = 0; k < 4; ++k) bw[k] = *(const bfrag*)&bp[32*k + 8*lq];
  };
  auto stageX = [&](float4 v) {
    const int node = tid >> 2, c = 4*(tid & 3);
    unsigned short s0 = f2b(v.x), s1 = f2b(v.y), s2 = f2b(v.z), s3 = f2b(v.w);
    us4 q = {s0, s1, s2, s3};
    *(us4*)&diffb[node*PD + c] = q;
    difT[(c+0)*PT + node] = s0; difT[(c+1)*PT + node] = s1;
    difT[(c+2)*PT + node] = s2; difT[(c+3)*PT + node] = s3;
  };

  // weight bases + biases
  const unsigned short* bpr0 = wt + WT0G_OFF + (16*j      + ln)*256;
  const unsigned short* bpu0 = wt + WT0G_OFF + (16*(4+j)  + ln)*256;
  const unsigned short* bpc0 = wt + WT0C_OFF + (16*j + ln)*256;
  const unsigned short* bpr1 = wt + WT1G_OFF + (16*j     + ln)*384;
  const unsigned short* bpu1 = wt + WT1G_OFF + (16*(4+j) + ln)*384;
  const unsigned short* bpc1 = wt + WT1C_OFF + (16*j + ln)*384;
  const float bgr0 = b0g[16*j + ln], bgu0 = b0g[64 + 16*j + ln], bcv0 = b0c[16*j + ln];
  const float bgr1 = b1g[16*j + ln], bgu1 = b1g[64 + 16*j + ln], bcv1 = b1c[16*j + ln];

  // A-column offset lists (merged layout)
  const int kofsG0[8]  = {0, 32, 64, 96, 128, 160, 192, 224};
  const int kofs0[8]   = {0, 32, 128, 160, 192, 224, 256, 288};
  const int kofsG1[12] = {64, 96, 128, 160, 192, 224, 320, 352, 384, 416, 448, 480};
  const int kofsC1[12] = {64, 96, 128, 160, 192, 224, 384, 416, 448, 480, 256, 288};

  ffrag h0m[4] = {fz, fz, fz, fz}, h1m[4] = {fz, fz, fz, fz};
  bfrag brg[4], bug[4], bw4[4];

  // Prologue: zero cols [48,512) (pad + h0 dm0/dm12 + h1 dm0/dm12 = 0 at t=0)
  for (int i = tid; i < N_*464; i += 512) {
    int row = i / 464, c = i - row*464;
    diffb[row*PD + 48 + c] = 0;
  }
  float4 xv = *(const float4*)&xseq[(size_t)(b*T_)*N_*DIN_ + 4*tid];
  stageX(xv);
  { int tn = 1 < L ? 1 : L - 1;
    xv = *(const float4*)&xseq[(size_t)(b*T_ + tn)*N_*DIN_ + 4*tid]; }
  preb4(brg, bpr0); preb4(bug, bpu0);      // gate0 ring prefill
  SYNC();
  diffuse(0, 16);                          // x(0) dm12
  SYNC();

#pragma clang loop unroll(disable)
  for (int t = 0; t < L; ++t) {
    // ---- P1: gate0 (cols 0-255) -> r0,u0; dump rh0 (cols 256-319, difT 16-79)
    ffrag u0s[4], rh[4];
    {
      ffrag ga[4][2] = {{fz, fz}, {fz, fz}, {fz, fz}, {fz, fz}};
      gateO<8>(ga, brg, bug, bpr0, bpu0, arowB, kofsG0, lq);
#pragma unroll
      for (int i = 0; i < 4; ++i)
#pragma unroll
        for (int r = 0; r < 4; ++r) {
          float rr = sigm(ga[i][0][r] + bgr0);
          rh[i][r]  = rr * h0m[i][r];
          u0s[i][r] = sigm(ga[i][1][r] + bgu0);
        }
    }
    dumpCell(rh, 256);
    preb4(bw4, bpc0);                      // cand0 ring prefill
    SYNC();                                              // BAR2
    // ---- P2: rh0 dm12 -> cols 128-255 (overwrite h0 dm12; gate0 done)
    diffuse(1, 128); diffuse(2, 160); diffuse(3, 192); diffuse(4, 224);
    SYNC();                                              // BAR3
    // ---- P3: cand0 -> h0'; dump h0' (cols 64-127, difT 16-79)
    {
      ffrag ca[4] = {fz, fz, fz, fz};
      candR<8>(ca, bw4, arowB, kofs0, bpc0, lq);
#pragma unroll
      for (int i = 0; i < 4; ++i)
#pragma unroll
        for (int r = 0; r < 4; ++r) {
          float cc = tanh_(ca[i][r] + bcv0);
          float uu = u0s[i][r];
          h0m[i][r] = uu*h0m[i][r] + (1.f - uu)*cc;
        }
    }
    dumpCell(h0m, 64);
    SYNC();                                              // BAR4
    // ---- P4: h0' dm12 -> cols 128-255 (overwrite rh0 dm12; cand0 done);
    //          stage x(t+1) (cols 0-15, difT 0-15); prefill gate1 ring
    preb4(brg, bpr1); preb4(bug, bpu1);
    diffuse(1, 128); diffuse(2, 160); diffuse(3, 192); diffuse(4, 224);
    stageX(xv);
    { int tn = t + 2 < L ? t + 2 : L - 1;
      xv = *(const float4*)&xseq[(size_t)(b*T_ + tn)*N_*DIN_ + 4*tid]; }
    SYNC();                                              // BAR5
    // ---- P5: x(t+1) dm12 -> cols 16-47; gate1 (cols 64-255 + 320-511) -> r1,u1;
    //          dump rh1 (cols 256-319 — cand0 consumed rh0 dm0; difT 16-79)
    diffuse(0, 16);
    ffrag u1s[4], rh1[4];
    {
      ffrag ga[4][2] = {{fz, fz}, {fz, fz}, {fz, fz}, {fz, fz}};
      gateO<12>(ga, brg, bug, bpr1, bpu1, arowB, kofsG1, lq);
#pragma unroll
      for (int i = 0; i < 4; ++i)
#pragma unroll
        for (int r = 0; r < 4; ++r) {
          float rr = sigm(ga[i][0][r] + bgr1);
          rh1[i][r] = rr * h1m[i][r];
          u1s[i][r] = sigm(ga[i][1][r] + bgu1);
        }
    }
    dumpCell(rh1, 256);
    preb4(bw4, bpc1);                      // cand1 ring prefill
    SYNC();                                              // BAR6
    // ---- P6: rh1 dm12 -> cols 384-511 (overwrite h1 dm12; gate1 done)
    diffuse(1, 384); diffuse(2, 416); diffuse(3, 448); diffuse(4, 480);
    SYNC();                                              // BAR7
    // ---- P7: cand1 -> h1'; dump h1 (cols 320-383, difT 16-79)
    {
      ffrag ca[4] = {fz, fz, fz, fz};
      candR<12>(ca, bw4, arowB, kofsC1, bpc1, lq);
#pragma unroll
      for (int i = 0; i < 4; ++i)
#pragma unroll
        for (int r = 0; r < 4; ++r) {
          float cc = tanh_(ca[i][r] + bcv1);
          float uu = u1s[i][r];
          h1m[i][r] = uu*h1m[i][r] + (1.f - uu)*cc;
        }
    }
    dumpCell(h1m, 320);
    SYNC();                                              // BAR8
    // ---- P8: h1 dm12 -> cols 384-511 (overwrite rh1 dm12; cand1 done);
    //          prefill next gate0 ring
    preb4(brg, bpr0); preb4(bug, bpu0);
    diffuse(1, 384); diffuse(2, 416); diffuse(3, 448); diffuse(4, 480);
    SYNC();                                              // BAR9 (loop)
  }

  // Head: relu(h1) @ W_fc + b_fc, max over nodes
  {
    float* hb = (float*)lds;                  // [128][64]
#pragma unroll
    for (int i = 0; i < 4; ++i)
#pragma unroll
      for (int r = 0; r < 4; ++r) {
        float v = h1m[i][r];
        hb[(64*g + 16*i + 4*lq + r)*U_ + 16*j + ln] = v > 0.f ? v : 0.f;
      }
  }
  __syncthreads();
  float* hb = (float*)lds;
  float* lb = hb + N_*U_;
  if (tid < N_) {
    float lg[4];
#pragma unroll
    for (int jj = 0; jj < 4; ++jj) lg[jj] = bfc[jj];
    for (int ch = 0; ch < U_; ++ch) {
      float v = hb[tid*U_ + ch];
#pragma unroll
      for (int jj = 0; jj < 4; ++jj) lg[jj] += v * wfc[ch*4 + jj];
    }
#pragma unroll
    for (int jj = 0; jj < 4; ++jj) lb[tid*4 + jj] = lg[jj];
  }
  __syncthreads();
  if (tid < 4) {
    float m = lb[tid];
    for (int n = 1; n < N_; ++n) m = fmaxf(m, lb[n*4 + tid]);
    out[b*4 + tid] = m;
  }
}

extern "C" void kernel_launch(void* const* d_in, const int* in_sizes, int n_in,
                              void* d_out, int out_size, void* d_ws, size_t ws_size,
                              hipStream_t stream) {
  const float* xseq = (const float*)d_in[0];
  const int*   slen = (const int*)  d_in[1];
  const float* sup  = (const float*)d_in[2];
  const float* w0g  = (const float*)d_in[3];
  const float* b0g  = (const float*)d_in[4];
  const float* w0c  = (const float*)d_in[5];
  const float* b0c  = (const float*)d_in[6];
  const float* w1g  = (const float*)d_in[7];
  const float* b1g  = (const float*)d_in[8];
  const float* w1c  = (const float*)d_in[9];
  const float* b1c  = (const float*)d_in[10];
  const float* wfc  = (const float*)d_in[11];
  const float* bfc  = (const float*)d_in[12];
  float* out = (float*)d_out;
  unsigned short* wt = (unsigned short*)d_ws;

  (void)hipFuncSetAttribute((const void*)dcgru,
                            hipFuncAttributeMaxDynamicSharedMemorySize, LDS_BYTES);
  setup_wt<<<dim3((WT_TOTAL + 255)/256), dim3(256), 0, stream>>>(w0g, w0c, w1g, w1c, wt);
  setup_s2<<<dim3(64), dim3(256), 0, stream>>>(sup, wt + S2_OFF);
  dcgru<<<dim3(32), dim3(512), LDS_BYTES, stream>>>(
      xseq, slen, sup, b0g, b0c, b1g, b1c, wfc, bfc, wt, out);
}

// Round 12
// 2515.706 us; speedup vs baseline: 3.2277x; 1.7856x over previous
//
#include <hip/hip_runtime.h>

// Problem constants
#define B_   32
#define T_   256
#define N_   128
#define DIN_ 16
#define U_   64

// LDS (ushort): diffb [128 nodes][PD] node-major; difT [128 ch][PT] ch-major
#define PD 456
#define PT 136
#define LDS_BYTES ((N_*PD + N_*PT)*2)   // 151552 B

// Workspace (ushort elems)
#define WT0G_OFF 0
#define WT0C_OFF (128*256)
#define WT1G_OFF (WT0C_OFF + 64*256)
#define WT1C_OFF (WT1G_OFF + 128*384)
#define WT_TOTAL (WT1C_OFF + 64*384)
#define S2_OFF   WT_TOTAL                 // bf16 S2[128][128]
#define FIFO_OFF (S2_OFF + 128*128)       // h0' stream: [b][t%8] x 8192 ush (16KB)
#define FIFO_SLOT(bb,tt) (FIFO_OFF + ((bb)*8 + ((tt)&7))*8192)
// flags: 2048 ints (8KB). prod[b] at flg[b*32] (one 128B line per batch);
// cons[b] at flg[1024 + b*32].
#define FLG_BYTE ((FIFO_OFF + 32*8*8192)*2)
#define FLG_USH  4096
// dm12 stream: [b][t%4] x 16384 ush (32KB) — byte image of diffb cols 64-191 per node
#define FIFO2_OFF (FIFO_OFF + 32*8*8192 + FLG_USH)
#define FIFO2_SLOT(bb,tt) (FIFO2_OFF + ((bb)*4 + ((tt)&3))*16384)

typedef __attribute__((ext_vector_type(8))) short bfrag;
typedef __attribute__((ext_vector_type(4))) float ffrag;
typedef __attribute__((ext_vector_type(4))) unsigned short us4;
typedef __attribute__((ext_vector_type(2))) unsigned short us2;
typedef unsigned long long ull;

// LDS-only barrier (no vmcnt drain)
#define SYNC() asm volatile("s_waitcnt lgkmcnt(0)\n\ts_barrier" ::: "memory")
#define MFMA16(a,b,c) __builtin_amdgcn_mfma_f32_16x16x32_bf16(a,b,c,0,0,0)

__device__ __forceinline__ unsigned short f2b(float x) {
  union { float f; unsigned u; } v; v.f = x;
  return (unsigned short)((v.u + 0x7fffu + ((v.u >> 16) & 1u)) >> 16);
}
__device__ __forceinline__ float sigm(float x) {
  float e = __expf(-x);
  return __builtin_amdgcn_rcpf(1.f + e);
}
__device__ __forceinline__ float tanh_(float x) {
  float e = __expf(2.f * x);
  return 1.f - 2.f * __builtin_amdgcn_rcpf(1.f + e);
}

// L0 gate k-map (K=256): [x dm0 16 | x dm12 32 | zero 16 | h dm0 64 | h dm12 128]
__device__ __forceinline__ float wval0(const float* w, int ncol, int co, int k) {
  if (k < 16)  return w[(k*3+0)*ncol+co] - w[(k*3+2)*ncol+co];
  if (k < 48)  { int j=k-16, c=j>>1;
                 return (j&1) ? 2.f*w[(c*3+2)*ncol+co] : w[(c*3+1)*ncol+co]; }
  if (k < 64)  return 0.f;
  if (k < 128) { int c=16+(k-64); return w[(c*3+0)*ncol+co] - w[(c*3+2)*ncol+co]; }
  { int j=k-128, c=16+(j>>1);
    return (j&1) ? 2.f*w[(c*3+2)*ncol+co] : w[(c*3+1)*ncol+co]; }
}
// L1 gate k-map (K=384): [h0' dm0 64 | h0' dm12 128 | h1 dm0 64 | h1 dm12 128]
__device__ __forceinline__ float wval1(const float* w, int ncol, int co, int k) {
  if (k < 64)  return w[(k*3+0)*ncol+co] - w[(k*3+2)*ncol+co];
  if (k < 192) { int j=k-64, c=j>>1;
                 return (j&1) ? 2.f*w[(c*3+2)*ncol+co] : w[(c*3+1)*ncol+co]; }
  if (k < 256) { int c=64+(k-192); return w[(c*3+0)*ncol+co] - w[(c*3+2)*ncol+co]; }
  { int j=k-256, c=64+(j>>1);
    return (j&1) ? 2.f*w[(c*3+2)*ncol+co] : w[(c*3+1)*ncol+co]; }
}
// cand k-orders (rh double-buffered):
// L0 cand cols: [x/zero 0-63 | rh dm12 @128-255 | rh dm0 @256-319]
__device__ __forceinline__ float wval0c(const float* w, int ncol, int co, int k) {
  if (k < 64)  return wval0(w, ncol, co, k);
  if (k < 192) return wval0(w, ncol, co, k + 64);
  return wval0(w, ncol, co, k - 128);
}
// L1 cand cols: [h0' 0-191 | rh dm12 @256-383 | rh dm0 @384-447]
__device__ __forceinline__ float wval1c(const float* w, int ncol, int co, int k) {
  if (k < 192) return wval1(w, ncol, co, k);
  if (k < 320) return wval1(w, ncol, co, k + 64);
  return wval1(w, ncol, co, k - 128);
}

__global__ void setup_wt(const float* __restrict__ w0g, const float* __restrict__ w0c,
                         const float* __restrict__ w1g, const float* __restrict__ w1c,
                         unsigned short* __restrict__ wt) {
  int i = blockIdx.x * blockDim.x + threadIdx.x;
  if (i >= WT_TOTAL) return;
  float v;
  if (i < WT0C_OFF)      { int co = i >> 8, k = i & 255;                 v = wval0 (w0g, 128, co, k); }
  else if (i < WT1G_OFF) { int j = i - WT0C_OFF; v = wval0c(w0c, 64, j >> 8, j & 255); }
  else if (i < WT1C_OFF) { int j = i - WT1G_OFF; v = wval1 (w1g, 128, j / 384, j % 384); }
  else                   { int j = i - WT1C_OFF; v = wval1c(w1c, 64, j / 384, j % 384); }
  wt[i] = f2b(v);
}

__global__ void setup_s2(const float* __restrict__ sup, unsigned short* __restrict__ s2) {
  int idx = blockIdx.x * blockDim.x + threadIdx.x;
  int i = idx >> 7, j = idx & 127;
  float acc = 0.f;
#pragma unroll 4
  for (int k = 0; k < 128; ++k) acc += sup[i*128 + k] * sup[k*128 + j];
  s2[idx] = f2b(acc);
}

__global__ void zero_flags(unsigned short* __restrict__ wt) {
  int* flg = (int*)((char*)wt + FLG_BYTE);
  for (int i = threadIdx.x; i < 2048; i += blockDim.x) flg[i] = 0;
}

// Gate GEMM, REGISTER-RESIDENT weights: 4 m-tiles x {r,u}; zero vm ops in loop.
template<int KT>
__device__ __forceinline__ void gateR(ffrag (&acc)[4][2],
    const bfrag (&bwr)[KT], const bfrag (&bwu)[KT],
    const unsigned short* __restrict__ arowB, const int lq) {
#pragma unroll
  for (int ks = 0; ks < KT; ++ks) {
    bfrag a[4];
#pragma unroll
    for (int i = 0; i < 4; ++i)
      a[i] = *(const bfrag*)&arowB[16*i*PD + 32*ks + 8*lq];
#pragma unroll
    for (int i = 0; i < 4; ++i) {
      acc[i][0] = MFMA16(a[i], bwr[ks], acc[i][0]);
      acc[i][1] = MFMA16(a[i], bwu[ks], acc[i][1]);
    }
  }
}
// Cand GEMM: 4 m-tiles x 1 co; A-cols via ks-offset list; 4-deep streamed ring.
template<int KT>
__device__ __forceinline__ void candR(ffrag (&acc)[4], bfrag (&bw)[4],
    const unsigned short* __restrict__ arowB, const int (&kofs)[KT],
    const unsigned short* __restrict__ bpc, const int lq) {
#pragma unroll
  for (int ks = 0; ks < KT; ++ks) {
    const int k = ks & 3;
    bfrag a[4];
#pragma unroll
    for (int i = 0; i < 4; ++i)
      a[i] = *(const bfrag*)&arowB[16*i*PD + kofs[ks] + 8*lq];
    bfrag bc = bw[k];
    if (ks + 4 < KT) bw[k] = *(const bfrag*)&bpc[32*(ks+4) + 8*lq];
#pragma unroll
    for (int i = 0; i < 4; ++i) acc[i] = MFMA16(a[i], bc, acc[i]);
  }
}

// launch_bounds(512, 1): LDS (151KB) caps at 1 block/CU anyway; declaring 2
// blocks/CU was silently budgeting 128 VGPR/wave (512 VGPR / 4 waves/SIMD).
// With 1 block/CU the allocator gets the full 256 VGPR/wave at 2 waves/SIMD.
__global__ __launch_bounds__(512, 1) void dcgru(
    const float* __restrict__ xseq, const int* __restrict__ slen,
    const float* __restrict__ sup,
    const float* __restrict__ b0g, const float* __restrict__ b0c,
    const float* __restrict__ b1g, const float* __restrict__ b1c,
    const float* __restrict__ wfc, const float* __restrict__ bfc,
    unsigned short* __restrict__ wt, float* __restrict__ out) {
  extern __shared__ unsigned short lds[];
  unsigned short* diffb = lds;
  unsigned short* difT  = lds + N_*PD;
  // XCD-local A/B pairing (A=x, B=x+8 share XCD under round-robin dispatch)
  const int b    = (blockIdx.x & 7) | ((blockIdx.x >> 4) << 3);
  const int eta  = (blockIdx.x >> 3) & 1;
  const int tid  = threadIdx.x;
  const int w    = tid >> 6;              // wave 0..7
  const int j    = w & 3;                 // ch-tile: ch [16j, 16j+16)
  const int g    = w >> 2;                // node-half: m-tiles 4g..4g+3 (64 nodes)
  const int ln   = tid & 15;
  const int lq   = (tid >> 4) & 3;
  const int L    = slen[b];
  int* flg  = (int*)((char*)wt + FLG_BYTE);
  int* prod = flg + b*32;                 // private 128B line per batch
  int* cons = flg + 1024 + b*32;          // private 128B line per batch
  const unsigned short* __restrict__ arowB = diffb + (64*g + ln)*PD;
  const ffrag fz = {0.f, 0.f, 0.f, 0.f};

  // S / S2 A-frags for diffuse strip w (1 strip, 8 bfrags = 32 VGPR)
  bfrag Sf[4], S2f[4];
#pragma unroll
  for (int ks = 0; ks < 4; ++ks) {
    const float* pS = sup + (16*w + ln)*N_ + 32*ks + 8*lq;
    union { bfrag v; unsigned short u[8]; } tmp;
#pragma unroll
    for (int jj = 0; jj < 8; ++jj) tmp.u[jj] = f2b(pS[jj]);
    Sf[ks] = tmp.v;
    S2f[ks] = *(const bfrag*)&wt[S2_OFF + (16*w + ln)*N_ + 32*ks + 8*lq];
  }

  // diffuse ch-tile nt for strip w: dm1=S@xc, dm2=S2@xc; cols colc + 2*ln + {0,1}
  auto diffuse = [&](int nt, int colc) {
    bfrag bf[4];
#pragma unroll
    for (int ks = 0; ks < 4; ++ks)
      bf[ks] = *(const bfrag*)&difT[(16*nt + ln)*PT + 32*ks + 8*lq];
    ffrag a1 = fz, a2 = fz;
#pragma unroll
    for (int ks = 0; ks < 4; ++ks) {
      a1 = MFMA16(Sf[ks],  bf[ks], a1);
      a2 = MFMA16(S2f[ks], bf[ks], a2);
    }
    const int n0 = 16*w + 4*lq;
    const int col = colc + 2*ln;
#pragma unroll
    for (int r = 0; r < 4; ++r) {
      us2 pq = {f2b(a1[r]), f2b(a2[r])};
      *(us2*)&diffb[(n0 + r)*PD + col] = pq;
    }
  };
  // dump wave's 4m x 1ch C-frags into both layouts
  auto dumpCell = [&](ffrag (&v)[4], int colBase, int rowBase) {
    const int chh = 16*j + ln;
#pragma unroll
    for (int i = 0; i < 4; ++i) {
      const int n0 = 64*g + 16*i + 4*lq;
      unsigned short sv[4];
#pragma unroll
      for (int r = 0; r < 4; ++r) sv[r] = f2b(v[i][r]);
#pragma unroll
      for (int r = 0; r < 4; ++r) diffb[(n0 + r)*PD + colBase + chh] = sv[r];
      us4 q = {sv[0], sv[1], sv[2], sv[3]};
      *(us4*)&difT[(rowBase + chh)*PT + n0] = q;
    }
  };
  auto prebC = [&](bfrag (&bw)[4], const unsigned short* bpc) {
#pragma unroll
    for (int k = 0; k < 4; ++k) bw[k] = *(const bfrag*)&bpc[32*k + 8*lq];
  };
  auto waitge = [&](int* p, int seq) {
    if ((tid & 63) == 0) {
      int it = 0;
      while (__hip_atomic_load(p, __ATOMIC_RELAXED, __HIP_MEMORY_SCOPE_AGENT) < seq) {
        __builtin_amdgcn_s_sleep(1);
        if (++it > (1 << 24)) break;            // failsafe: never hard-hang
      }
    }
  };

  bfrag bw4[4];

  if (eta == 0) {
    // ===== Block A: L0. cols [x 0-15|x dm12 16-47|z 48-63|h dm0 64-127|h dm12 128-255|rh dm0 256-319]
    // h0' dm12 (cols 128-255) is computed at END of each step (after cand) and
    // shipped to B via FIFO2 — B does not re-diffuse h0'.
    bfrag bwr[8], bwu[8];
    {
      const unsigned short* bpr = wt + WT0G_OFF + (16*j      + ln)*256;
      const unsigned short* bpu = wt + WT0G_OFF + (16*(4+j)  + ln)*256;
#pragma unroll
      for (int ks = 0; ks < 8; ++ks) {
        bwr[ks] = *(const bfrag*)&bpr[32*ks + 8*lq];
        bwu[ks] = *(const bfrag*)&bpu[32*ks + 8*lq];
      }
    }
    const unsigned short* bpc = wt + WT0C_OFF + (16*j + ln)*256;
    const float bgr = b0g[16*j + ln], bgu = b0g[64 + 16*j + ln];
    const float bcv = b0c[16*j + ln];
    const int kofs0[8] = {0, 32, 128, 160, 192, 224, 256, 288};
    ffrag h0m[4] = {fz, fz, fz, fz};

    // zero cols [48,256): zero-pad block + h dm0 + h dm12 for t=0 (h0 = 0)
    for (int i = tid; i < N_*208; i += 512) {
      int row = i / 208, c = i - row*208;
      diffb[row*PD + 48 + c] = 0;
    }
    float4 xv = *(const float4*)&xseq[(size_t)(b*T_)*N_*DIN_ + 4*tid];

#pragma clang loop unroll(disable)
    for (int t = 0; t < L; ++t) {
      { // P1: stage x (cols 0-15 / difT rows 0-15). h-dumps moved to step end.
        const int node = tid >> 2, c = 4*(tid & 3);
        unsigned short s0 = f2b(xv.x), s1 = f2b(xv.y), s2 = f2b(xv.z), s3 = f2b(xv.w);
        us4 q = {s0, s1, s2, s3};
        *(us4*)&diffb[node*PD + c] = q;
        difT[(c+0)*PT + node] = s0; difT[(c+1)*PT + node] = s1;
        difT[(c+2)*PT + node] = s2; difT[(c+3)*PT + node] = s3;
        int tn = t + 1 < L ? t + 1 : L - 1;
        xv = *(const float4*)&xseq[(size_t)(b*T_ + tn)*N_*DIN_ + 4*tid];
      }
      SYNC();                                            // BAR1
      diffuse(0, 16);                                    // x dm12 only
      SYNC();                                            // BAR2
      ffrag u0s[4], rh[4];
      {
        ffrag ga[4][2] = {{fz, fz}, {fz, fz}, {fz, fz}, {fz, fz}};
        gateR<8>(ga, bwr, bwu, arowB, lq);
#pragma unroll
      for (int i = 0; i < 4; ++i)
#pragma unroll
          for (int r = 0; r < 4; ++r) {
            float rr = sigm(ga[i][0][r] + bgr);
            rh[i][r]  = rr * h0m[i][r];
            u0s[i][r] = sigm(ga[i][1][r] + bgu);
          }
      }
      dumpCell(rh, 256, 16);                 // rh dm0 -> fresh cols (no gate WAR)
      prebC(bw4, bpc);
      SYNC();                                            // BAR3
      diffuse(1, 128); diffuse(2, 160); diffuse(3, 192); diffuse(4, 224);  // rh dm12
      SYNC();                                            // BAR4
      {
        ffrag ca[4] = {fz, fz, fz, fz};
        candR<8>(ca, bw4, arowB, kofs0, bpc, lq);
#pragma unroll
        for (int i = 0; i < 4; ++i)
#pragma unroll
          for (int r = 0; r < 4; ++r) {
            float cc = tanh_(ca[i][r] + bcv);
            float uu = u0s[i][r];
            h0m[i][r] = uu*h0m[i][r] + (1.f - uu)*cc;
          }
      }
      // h0'(t) ready. Dump both layouts (cols 64-127 disjoint from cand reads).
      dumpCell(h0m, 64, 16);
      if (t >= 4) waitge(cons, t - 3);                   // FIFO2 depth-4 backpressure
      { // send h0' ch-major [64 ch][128 nodes] (register source)
        unsigned short* slot = wt + FIFO_SLOT(b, t);
        const int chh = 16*j + ln;
#pragma unroll
        for (int i = 0; i < 4; ++i) {
          const int n0 = 64*g + 16*i + 4*lq;
          us4 q = {f2b(h0m[i][0]), f2b(h0m[i][1]), f2b(h0m[i][2]), f2b(h0m[i][3])};
          *(us4*)&slot[chh*128 + n0] = q;
        }
      }
      SYNC();                                            // BAR5: h0' difT dump visible
      // h0' dm12 -> cols 128-255 (reused by next-step gate AND sent to B)
      diffuse(1, 128); diffuse(2, 160); diffuse(3, 192); diffuse(4, 224);
      SYNC();                                            // BAR6: dm12 image complete
      { // ship byte image of cols [128,256) -> FIFO2 (B maps to its cols [64,192))
        unsigned short* slot2 = wt + FIFO2_SLOT(b, t);
#pragma unroll
        for (int rep = 0; rep < 8; ++rep) {
          const int i = tid + 512*rep;
          const int node = i >> 5, off = (i & 31)*4;
          ull v = *(const ull*)&diffb[node*PD + 128 + off];
          *(ull*)&slot2[node*128 + off] = v;
        }
      }
      asm volatile("s_waitcnt vmcnt(0)" ::: "memory");    // drain both payloads
      if ((tid & 63) == 0)
        __hip_atomic_fetch_add(prod, 1, __ATOMIC_RELEASE, __HIP_MEMORY_SCOPE_AGENT);
    }
    return;
  }

  // ===== Block B: L1. cols [h0' dm0 0-63|h0' dm12 64-191|h1 dm0 192-255|h1/rh dm12 256-383|rh dm0 384-447]
  {
    // Resident gate weights: r_j, u_j, K=384 (24 bfrags = 96 VGPR)
    bfrag bwr[12], bwu[12];
    {
      const unsigned short* bpr = wt + WT1G_OFF + (16*j     + ln)*384;
      const unsigned short* bpu = wt + WT1G_OFF + (16*(4+j) + ln)*384;
#pragma unroll
      for (int ks = 0; ks < 12; ++ks) {
        bwr[ks] = *(const bfrag*)&bpr[32*ks + 8*lq];
        bwu[ks] = *(const bfrag*)&bpu[32*ks + 8*lq];
      }
    }
    const unsigned short* bpc = wt + WT1C_OFF + (16*j + ln)*384;
    const float bgr = b1g[16*j + ln], bgu = b1g[64 + 16*j + ln];
    const float bcv = b1c[16*j + ln];
    const int kofs1[12] = {0, 32, 64, 96, 128, 160, 256, 288, 320, 352, 384, 416};
    ffrag h1m[4] = {fz, fz, fz, fz};

#pragma clang loop unroll(disable)
    for (int t = 0; t < L; ++t) {
      waitge(prod, 8*(t + 1));               // all 8 A-waves published step t
      { // P1: recv h0'(t) -> diffb cols 0-63 + difT rows 0-63; dm12 image -> cols 64-191;
        // dump h1 (cols 192-255 / difT rows 64-127)
        const unsigned short* slot = wt + FIFO_SLOT(b, t);
#pragma unroll
        for (int rep = 0; rep < 4; ++rep) {
          const int idx = tid + 512*rep;
          const int ch = idx >> 5, n0 = (idx & 31)*4;
          ull v = __hip_atomic_load((const ull*)&slot[ch*128 + n0],
                                    __ATOMIC_RELAXED, __HIP_MEMORY_SCOPE_AGENT);
          *(ull*)&difT[ch*PT + n0] = v;
          union { ull u; unsigned short s[4]; } cv; cv.u = v;
#pragma unroll
          for (int jj = 0; jj < 4; ++jj) diffb[(n0 + jj)*PD + ch] = cv.s[jj];
        }
        const unsigned short* slot2 = wt + FIFO2_SLOT(b, t);
#pragma unroll
        for (int rep = 0; rep < 8; ++rep) {
          const int i = tid + 512*rep;
          const int node = i >> 5, off = (i & 31)*4;
          ull v = __hip_atomic_load((const ull*)&slot2[node*128 + off],
                                    __ATOMIC_RELAXED, __HIP_MEMORY_SCOPE_AGENT);
          *(ull*)&diffb[node*PD + 64 + off] = v;
        }
        dumpCell(h1m, 192, 64);
      }
      SYNC();                                            // BAR1
      if (tid == 0)
        __hip_atomic_fetch_add(cons, 1, __ATOMIC_RELEASE, __HIP_MEMORY_SCOPE_AGENT);
      diffuse(4, 256); diffuse(5, 288); diffuse(6, 320); diffuse(7, 352);  // h1 dm12 only
      SYNC();                                            // BAR2
      ffrag u1s[4], rh[4];
      {
        ffrag ga[4][2] = {{fz, fz}, {fz, fz}, {fz, fz}, {fz, fz}};
        gateR<12>(ga, bwr, bwu, arowB, lq);
#pragma unroll
        for (int i = 0; i < 4; ++i)
#pragma unroll
          for (int r = 0; r < 4; ++r) {
            float rr = sigm(ga[i][0][r] + bgr);
            rh[i][r]  = rr * h1m[i][r];
            u1s[i][r] = sigm(ga[i][1][r] + bgu);
          }
      }
      dumpCell(rh, 384, 64);                 // rh dm0 -> fresh cols
      prebC(bw4, bpc);
      SYNC();                                            // BAR3
      diffuse(4, 256); diffuse(5, 288); diffuse(6, 320); diffuse(7, 352);  // rh dm12
      SYNC();                                            // BAR4
      {
        ffrag ca[4] = {fz, fz, fz, fz};
        candR<12>(ca, bw4, arowB, kofs1, bpc, lq);
#pragma unroll
        for (int i = 0; i < 4; ++i)
#pragma unroll
          for (int r = 0; r < 4; ++r) {
            float cc = tanh_(ca[i][r] + bcv);
            float uu = u1s[i][r];
            h1m[i][r] = uu*h1m[i][r] + (1.f - uu)*cc;
          }
      }
      SYNC();                                            // BAR5 (cand reads done)
    }

    // Head: relu(h1) @ W_fc + b_fc, max over nodes
    {
      float* hb = (float*)lds;                  // [128][64]
#pragma unroll
      for (int i = 0; i < 4; ++i)
#pragma unroll
        for (int r = 0; r < 4; ++r) {
          float v = h1m[i][r];
          hb[(64*g + 16*i + 4*lq + r)*U_ + 16*j + ln] = v > 0.f ? v : 0.f;
        }
    }
    __syncthreads();
    float* hb = (float*)lds;
    float* lb = hb + N_*U_;
    if (tid < N_) {
      float lg[4];
#pragma unroll
      for (int jj = 0; jj < 4; ++jj) lg[jj] = bfc[jj];
      for (int ch = 0; ch < U_; ++ch) {
        float v = hb[tid*U_ + ch];
#pragma unroll
        for (int jj = 0; jj < 4; ++jj) lg[jj] += v * wfc[ch*4 + jj];
      }
#pragma unroll
      for (int jj = 0; jj < 4; ++jj) lb[tid*4 + jj] = lg[jj];
    }
    __syncthreads();
    if (tid < 4) {
      float m = lb[tid];
      for (int n = 1; n < N_; ++n) m = fmaxf(m, lb[n*4 + tid]);
      out[b*4 + tid] = m;
    }
  }
}

extern "C" void kernel_launch(void* const* d_in, const int* in_sizes, int n_in,
                              void* d_out, int out_size, void* d_ws, size_t ws_size,
                              hipStream_t stream) {
  const float* xseq = (const float*)d_in[0];
  const int*   slen = (const int*)  d_in[1];
  const float* sup  = (const float*)d_in[2];
  const float* w0g  = (const float*)d_in[3];
  const float* b0g  = (const float*)d_in[4];
  const float* w0c  = (const float*)d_in[5];
  const float* b0c  = (const float*)d_in[6];
  const float* w1g  = (const float*)d_in[7];
  const float* b1g  = (const float*)d_in[8];
  const float* w1c  = (const float*)d_in[9];
  const float* b1c  = (const float*)d_in[10];
  const float* wfc  = (const float*)d_in[11];
  const float* bfc  = (const float*)d_in[12];
  float* out = (float*)d_out;
  unsigned short* wt = (unsigned short*)d_ws;

  (void)hipFuncSetAttribute((const void*)dcgru,
                            hipFuncAttributeMaxDynamicSharedMemorySize, LDS_BYTES);
  zero_flags<<<dim3(1), dim3(512), 0, stream>>>(wt);
  setup_wt<<<dim3((WT_TOTAL + 255)/256), dim3(256), 0, stream>>>(w0g, w0c, w1g, w1c, wt);
  setup_s2<<<dim3(64), dim3(256), 0, stream>>>(sup, wt + S2_OFF);
  dcgru<<<dim3(64), dim3(512), LDS_BYTES, stream>>>(
      xseq, slen, sup, b0g, b0c, b1g, b1c, wfc, bfc, wt, out);
}